// Round 9
// baseline (499.681 us; speedup 1.0000x reference)
//
#include <hip/hip_runtime.h>
#include <math.h>

// SwinV2 block, MI355X. All GEMMs in bf16 MFMA (16x16x32), fp32 accumulate.
// Round 9: GEMM -> 2-slot dbuf (64 KiB LDS, 2 blocks/CU for cross-block overlap);
// attn reverted to per-(win,head,qb) blocks + one-pass softmax (no row-max; C=scale+16).
// Requires ws_size >= 208 MiB.

#define HEADS 16
#define HD 32
#define NTOK 256
#define DIMC 512
#define HIDDEN 2048

typedef __attribute__((ext_vector_type(8))) short bf16x8;
typedef __attribute__((ext_vector_type(4))) float f32x4;
typedef __attribute__((ext_vector_type(8))) unsigned short ushort8;

#define MFMA16(a, b, c) __builtin_amdgcn_mfma_f32_16x16x32_bf16((a), (b), (c), 0, 0, 0)
#define WAIT_VM(N) asm volatile("s_waitcnt vmcnt(" #N ")" ::: "memory")
#define WAIT_LGKM0 asm volatile("s_waitcnt lgkmcnt(0)" ::: "memory")

__device__ __forceinline__ unsigned short f2bf(float f) {
  union { float f; unsigned u; } v; v.f = f;
  unsigned r = v.u + 0x7FFFu + ((v.u >> 16) & 1u);
  return (unsigned short)(r >> 16);
}
__device__ __forceinline__ float bf2f(unsigned short h) {
  union { unsigned u; float f; } v; v.u = ((unsigned)h) << 16; return v.f;
}
__device__ __forceinline__ void gload16(const void* g, void* l) {
  __builtin_amdgcn_global_load_lds(
      (const __attribute__((address_space(1))) unsigned int*)g,
      (__attribute__((address_space(3))) unsigned int*)l, 16, 0, 0);
}
__device__ __forceinline__ bf16x8 ds_read128(const unsigned short* p) {
  unsigned off = (unsigned)(size_t)(const __attribute__((address_space(3))) unsigned short*)p;
  bf16x8 r;
  asm volatile("ds_read_b128 %0, %1" : "=v"(r) : "v"(off));
  return r;
}
__device__ __forceinline__ int band(int x) { return x < 48 ? 0 : (x < 56 ? 1 : 2); }

__device__ __forceinline__ float gelu_fast(float x) {
  float u2 = x * (1.5957691216f + 0.0713548163f * x * x);
  u2 = fminf(u2, 80.f);
  float e = __expf(u2);
  return x * (e / (e + 1.f));
}

// ------------------- 256x256 GEMM mainloop, 512 threads (8 waves, 2Mx4N) -------------------
// 2-slot double-buffer (64 KiB LDS -> 2 blocks/CU). Read-ahead fragments; stage(t+1)
// issued at top of iter t; single vmcnt(0)+barrier per K-step. Cross-block TLP hides
// the residual drain (m114 mechanism).
__device__ __forceinline__ void gemm256_main(const unsigned short* Ab, const unsigned short* Bb,
                                             int K, unsigned short* aT, unsigned short* bT,
                                             f32x4 (&acc)[8][4]) {
  const int tid = threadIdx.x;
  const int w = tid >> 6, lane = tid & 63;
  const int cl = lane & 15, g = lane >> 4;
  const int wr = (w >> 2) * 128, wc = (w & 3) * 64;
  const int off0 = (2 * w) * 1024 + lane * 16;
  const int off1 = (2 * w + 1) * 1024 + lane * 16;
  const int r0 = off0 >> 6, c0 = ((off0 >> 4) & 3) ^ ((r0 >> 1) & 3);
  const int r1 = off1 >> 6, c1 = ((off1 >> 4) & 3) ^ ((r1 >> 1) & 3);
  const char* Ac = (const char*)Ab;
  const char* Bc = (const char*)Bb;
  const size_t sA0 = (size_t)r0 * (K * 2) + (size_t)c0 * 16;
  const size_t sA1 = (size_t)r1 * (K * 2) + (size_t)c1 * 16;
  const int T = K >> 5;
  int offB[4], offA0[4], offA1[4];
#pragma unroll
  for (int i = 0; i < 4; i++) {
    int rowb = wc + i * 16 + cl;
    offB[i] = rowb * 32 + ((g ^ ((rowb >> 1) & 3)) * 8);
    int rowa = wr + i * 16 + cl;
    offA0[i] = rowa * 32 + ((g ^ ((rowa >> 1) & 3)) * 8);
    int rowa1 = wr + 64 + i * 16 + cl;
    offA1[i] = rowa1 * 32 + ((g ^ ((rowa1 >> 1) & 3)) * 8);
  }
  // prologue: stage slot 0
  gload16(Ac + sA0, (char*)aT + off0);
  gload16(Ac + sA1, (char*)aT + off1);
  gload16(Bc + sA0, (char*)bT + off0);
  gload16(Bc + sA1, (char*)bT + off1);
  WAIT_VM(0);
  __builtin_amdgcn_s_barrier();
  bf16x8 bfv[4], af[4];
#pragma unroll
  for (int ni = 0; ni < 4; ni++) bfv[ni] = ds_read128(bT + offB[ni]);
#pragma unroll
  for (int mi = 0; mi < 4; mi++) af[mi] = ds_read128(aT + offA0[mi]);

  for (int t = 0; t < T; t++) {
    const int cur = (t & 1) * 8192, nxt = 8192 - cur;
    // stage(t+1) into the other slot (its last readers finished before prev barrier)
    if (t + 1 < T) {
      size_t kb = (size_t)(t + 1) * 64;
      gload16(Ac + sA0 + kb, (char*)aT + nxt * 2 + off0);
      gload16(Ac + sA1 + kb, (char*)aT + nxt * 2 + off1);
      gload16(Bc + sA0 + kb, (char*)bT + nxt * 2 + off0);
      gload16(Bc + sA1 + kb, (char*)bT + nxt * 2 + off1);
    }
    WAIT_LGKM0;
    __builtin_amdgcn_sched_barrier(0);
    __builtin_amdgcn_s_setprio(1);
#pragma unroll
    for (int mi = 0; mi < 4; mi++)
#pragma unroll
      for (int ni = 0; ni < 4; ni++) acc[mi][ni] = MFMA16(af[mi], bfv[ni], acc[mi][ni]);
    __builtin_amdgcn_s_setprio(0);
    bf16x8 af2[4];
#pragma unroll
    for (int mi = 0; mi < 4; mi++) af2[mi] = ds_read128(aT + cur + offA1[mi]);
    WAIT_LGKM0;
    __builtin_amdgcn_sched_barrier(0);
    __builtin_amdgcn_s_setprio(1);
#pragma unroll
    for (int mi = 0; mi < 4; mi++)
#pragma unroll
      for (int ni = 0; ni < 4; ni++) acc[4 + mi][ni] = MFMA16(af2[mi], bfv[ni], acc[4 + mi][ni]);
    __builtin_amdgcn_s_setprio(0);
    if (t + 1 < T) {
      WAIT_VM(0);  // stage(t+1) landed (issued one full iter ago; co-resident block hides rest)
      __builtin_amdgcn_s_barrier();
#pragma unroll
      for (int ni = 0; ni < 4; ni++) bfv[ni] = ds_read128(bT + nxt + offB[ni]);
#pragma unroll
      for (int mi = 0; mi < 4; mi++) af[mi] = ds_read128(aT + nxt + offA0[mi]);
    }
  }
}

__device__ __forceinline__ void xcd_swizzle(int& bm, int& bn) {
  int gy = gridDim.y;
  int nwg = gridDim.x * gy;
  int flat = blockIdx.y * gridDim.x + blockIdx.x;
  int cpx = nwg >> 3;
  int swz = (flat & 7) * cpx + (flat >> 3);
  bm = swz / gy;
  bn = swz % gy;
}

// ------------------- QKV GEMM: bias + scatter to q/k/v [win][head][tok][hd] -------------------
__global__ __launch_bounds__(512, 2) void gemm_qkv(const unsigned short* A,
                                                   const unsigned short* Bw, const float* qbias,
                                                   const float* vbias, unsigned short* qo,
                                                   unsigned short* ko, unsigned short* vo) {
  __shared__ unsigned short aT[2 * 8192];
  __shared__ unsigned short bT[2 * 8192];
  int bm, bn;
  xcd_swizzle(bm, bn);
  f32x4 acc[8][4] = {};
  gemm256_main(A + (size_t)bm * 256 * DIMC, Bw + (size_t)bn * 256 * DIMC, DIMC, aT, bT, acc);
  int lane = threadIdx.x & 63, w = threadIdx.x >> 6;
  int wr = (w >> 2) * 128, wc = (w & 3) * 64, g = lane >> 4, cl = lane & 15;
  int which = bn >> 1;  // uniform per block: 0=q,1=k,2=v
  unsigned short* base = which == 0 ? qo : (which == 1 ? ko : vo);
#pragma unroll
  for (int ni = 0; ni < 4; ni++) {
    int gn = bn * 256 + wc + ni * 16 + cl;
    int wn = gn & 511, head = wn >> 5, hd = wn & 31;
    float bv = (which == 0) ? qbias[wn] : (which == 2 ? vbias[wn] : 0.f);
#pragma unroll
    for (int mi = 0; mi < 8; mi++) {
#pragma unroll
      for (int reg = 0; reg < 4; reg++) {
        int gm = bm * 256 + wr + mi * 16 + 4 * g + reg;
        int win = gm >> 8, tok = gm & 255;
        base[(((size_t)(win * HEADS + head)) * NTOK + tok) * HD + hd] =
            f2bf(acc[mi][ni][reg] + bv);
      }
    }
  }
}

// ------------------- generic GEMM: bias (+optional fast GELU) -> bf16 [M][N] -------------------
template <int GELU>
__global__ __launch_bounds__(512, 2) void gemm_epi(const unsigned short* A,
                                                   const unsigned short* Bw, const float* bias,
                                                   unsigned short* out, int N, int K) {
  __shared__ unsigned short aT[2 * 8192];
  __shared__ unsigned short bT[2 * 8192];
  int bm, bn;
  xcd_swizzle(bm, bn);
  f32x4 acc[8][4] = {};
  gemm256_main(A + (size_t)bm * 256 * K, Bw + (size_t)bn * 256 * K, K, aT, bT, acc);
  int lane = threadIdx.x & 63, w = threadIdx.x >> 6;
  int wr = (w >> 2) * 128, wc = (w & 3) * 64, g = lane >> 4, cl = lane & 15;
  float bv[4];
#pragma unroll
  for (int ni = 0; ni < 4; ni++) bv[ni] = bias[bn * 256 + wc + ni * 16 + cl];
#pragma unroll
  for (int mi = 0; mi < 8; mi++) {
#pragma unroll
    for (int reg = 0; reg < 4; reg++) {
      int gm = bm * 256 + wr + mi * 16 + 4 * g + reg;
      unsigned short* rowp = out + (size_t)gm * N + bn * 256 + wc + cl;
#pragma unroll
      for (int ni = 0; ni < 4; ni++) {
        float val = acc[mi][ni][reg] + bv[ni];
        if (GELU) val = gelu_fast(val);
        rowp[ni * 16] = f2bf(val);
      }
    }
  }
}

// ------------------- fused window attention -------------------
// block = (win, head, qb) ; 256 threads = 4 waves ; one-pass softmax, no row-max
// (C = scale + 16 is a guaranteed upper bound on S = scale*cos + rpb + mask).
__global__ __launch_bounds__(256) void attn_kernel(const unsigned short* qg,
                                                   const unsigned short* kg,
                                                   const unsigned short* vg, const float* rpbt,
                                                   const float* logit_scale,
                                                   unsigned short* attn_out) {
  __shared__ unsigned short kS[256 * 32];
  __shared__ unsigned short vT[32 * 256];
  __shared__ unsigned short pS[64 * 256];

  int bid = blockIdx.x;
  int qb = bid & 3, h = (bid >> 2) & 15, win = bid >> 6;
  int tid = threadIdx.x, lane = tid & 63, w = tid >> 6;
  int g = lane >> 4, cl = lane & 15;
  const size_t whbase = ((size_t)(win * HEADS + h)) * NTOK * HD;
  const unsigned short* qwin = qg + whbase + (size_t)qb * 64 * HD;
  const unsigned short* kwin = kg + whbase;
  const unsigned short* vwin = vg + whbase;

#pragma unroll
  for (int i = 0; i < 4; i++) {
    int ci = i * 256 + tid, row = ci >> 2, gc = ci & 3;
    uint4 d = *(const uint4*)(kwin + row * 32 + gc * 8);
    *(uint4*)(kS + row * 32 + ((gc ^ ((row >> 1) & 3)) * 8)) = d;
  }
  {
    int tok = tid;
    ushort8 t0 = *(const ushort8*)(vwin + tok * 32);
    ushort8 t1 = *(const ushort8*)(vwin + tok * 32 + 8);
    ushort8 t2 = *(const ushort8*)(vwin + tok * 32 + 16);
    ushort8 t3 = *(const ushort8*)(vwin + tok * 32 + 24);
    int kc = tok >> 3, ki = tok & 7;
#pragma unroll
    for (int j = 0; j < 8; j++) {
      vT[(j)*256 + ((kc ^ (j & 7)) << 3) + ki] = t0[j];
      vT[(8 + j) * 256 + ((kc ^ ((8 + j) & 7)) << 3) + ki] = t1[j];
      vT[(16 + j) * 256 + ((kc ^ ((16 + j) & 7)) << 3) + ki] = t2[j];
      vT[(24 + j) * 256 + ((kc ^ ((24 + j) & 7)) << 3) + ki] = t3[j];
    }
  }
  __syncthreads();

  float scale = __expf(fminf(logit_scale[h], 4.6051702f));

  // normalize K rows in LDS (thread = row)
  {
    int row = tid;
    int sw = (row >> 1) & 3;
    ushort8 ch[4];
#pragma unroll
    for (int gc = 0; gc < 4; gc++) ch[gc] = *(const ushort8*)(kS + row * 32 + ((gc ^ sw) * 8));
    float ss = 0.f;
#pragma unroll
    for (int gc = 0; gc < 4; gc++)
#pragma unroll
      for (int j = 0; j < 8; j++) { float f = bf2f(ch[gc][j]); ss += f * f; }
    float rn = rsqrtf(fmaxf(ss, 1e-24f));
#pragma unroll
    for (int gc = 0; gc < 4; gc++) {
      ushort8 o;
#pragma unroll
      for (int j = 0; j < 8; j++) o[j] = f2bf(bf2f(ch[gc][j]) * rn);
      *(ushort8*)(kS + row * 32 + ((gc ^ sw) * 8)) = o;
    }
  }

  // q fragment, normalized in registers (lanes cl,16+cl,32+cl,48+cl share a row)
  bf16x8 qf;
  {
    int qrow = 16 * w + cl;
    ushort8 qraw = *(const ushort8*)(qwin + qrow * 32 + 8 * g);
    float qe[8];
    float ss = 0.f;
#pragma unroll
    for (int j = 0; j < 8; j++) { qe[j] = bf2f(qraw[j]); ss += qe[j] * qe[j]; }
    ss += __shfl_xor(ss, 16, 64);
    ss += __shfl_xor(ss, 32, 64);
    float rn = rsqrtf(fmaxf(ss, 1e-24f)) * scale;
#pragma unroll
    for (int j = 0; j < 8; j++) qf[j] = (short)f2bf(qe[j] * rn);
  }
  __syncthreads();

  // S = q @ K^T : 16 tiles of 16x16
  f32x4 acc[16];
#pragma unroll
  for (int ct = 0; ct < 16; ct++) {
    int kr = ct * 16 + cl;
    bf16x8 kf = *(const bf16x8*)(kS + kr * 32 + ((g ^ ((kr >> 1) & 3)) * 8));
    f32x4 z = {0.f, 0.f, 0.f, 0.f};
    acc[ct] = MFMA16(qf, kf, z);
  }

  // one-pass: + rpb + mask -> p = exp(S - C) -> LDS ; row sums
  int wh = (win >> 2) & 3, ww = win & 3;
  int bandcc = band(ww * 16 + cl);
  const float* rpbh = rpbt + h * 961;
  const float C = scale + 16.f;
  int baseidx[4], ridq[4];
#pragma unroll
  for (int reg = 0; reg < 4; reg++) {
    int qrow = qb * 64 + 16 * w + 4 * g + reg;
    int ri = qrow >> 4, ci = qrow & 15;
    ridq[reg] = 3 * band(wh * 16 + ri) + band(ww * 16 + ci);
    baseidx[reg] = (ri + 15) * 31 + (ci + 15 - cl);
  }
  float s4[4] = {0.f, 0.f, 0.f, 0.f};
#pragma unroll
  for (int ct = 0; ct < 16; ct++) {
    int brc = 3 * band(wh * 16 + ct);
#pragma unroll
    for (int reg = 0; reg < 4; reg++) {
      float v = acc[ct][reg] + rpbh[baseidx[reg] - ct * 31] +
                ((ridq[reg] != (brc + bandcc)) ? -100.f : 0.f);
      float p = __expf(v - C);
      s4[reg] += p;
      int row = 16 * w + 4 * g + reg;
      int c = ct * 16 + cl;
      pS[row * 256 + (((c >> 3) ^ (row & 7)) << 3) + (c & 7)] = f2bf(p);
    }
  }
#pragma unroll
  for (int reg = 0; reg < 4; reg++) {
#pragma unroll
    for (int o = 1; o < 16; o <<= 1) s4[reg] += __shfl_xor(s4[reg], o, 64);
  }

  // O = P @ V  (wave reads only its own P rows -> no barrier needed)
  f32x4 o0 = {0.f, 0.f, 0.f, 0.f}, o1 = {0.f, 0.f, 0.f, 0.f};
  int prow = 16 * w + cl;
#pragma unroll
  for (int ks = 0; ks < 8; ks++) {
    bf16x8 pf = *(const bf16x8*)(pS + prow * 256 + ((((ks * 4 + g)) ^ (prow & 7)) << 3));
    int kc = ks * 4 + g;
    bf16x8 vf0 = *(const bf16x8*)(vT + cl * 256 + ((kc ^ (cl & 7)) << 3));
    bf16x8 vf1 = *(const bf16x8*)(vT + (16 + cl) * 256 + ((kc ^ ((16 + cl) & 7)) << 3));
    o0 = MFMA16(pf, vf0, o0);
    o1 = MFMA16(pf, vf1, o1);
  }

#pragma unroll
  for (int reg = 0; reg < 4; reg++) {
    int row = 16 * w + 4 * g + reg;
    float linv = 1.f / s4[reg];
    size_t tokg = (size_t)win * NTOK + qb * 64 + row;
    attn_out[tokg * DIMC + h * 32 + cl] = f2bf(o0[reg] * linv);
    attn_out[tokg * DIMC + h * 32 + 16 + cl] = f2bf(o1[reg] * linv);
  }
}

// ------------------- prep kernels -------------------
__global__ __launch_bounds__(256) void cvt_bf16(const float* src, unsigned short* dst, int n8) {
  int i = blockIdx.x * 256 + threadIdx.x;
  if (i >= n8) return;
  const float* s = src + (size_t)i * 8;
  float4 a = *(const float4*)s, b = *(const float4*)(s + 4);
  ushort8 o;
  o[0] = f2bf(a.x); o[1] = f2bf(a.y); o[2] = f2bf(a.z); o[3] = f2bf(a.w);
  o[4] = f2bf(b.x); o[5] = f2bf(b.y); o[6] = f2bf(b.z); o[7] = f2bf(b.w);
  *(ushort8*)(dst + (size_t)i * 8) = o;
}

__device__ __forceinline__ float cpb_coord(int i) {
  float t = (float)(i - 15) * (8.f / 15.f);
  float s = (t > 0.f) ? 1.f : ((t < 0.f) ? -1.f : 0.f);
  return s * log2f(fabsf(t) + 1.f) * (1.f / 3.f);
}

__global__ __launch_bounds__(256) void cpb_kernel(const float* w1, const float* b1, const float* w2,
                                                  float* rpbt) {
  int i = blockIdx.x * 256 + threadIdx.x;
  if (i >= 961 * 16) return;
  int m = i >> 4, h = i & 15;
  int mi = m / 31, mj = m % 31;
  float c0 = cpb_coord(mi), c1 = cpb_coord(mj);
  float acc = 0.f;
  for (int j = 0; j < 512; j++) {
    float hv = fmaxf(w1[2 * j] * c0 + w1[2 * j + 1] * c1 + b1[j], 0.f);
    acc += hv * w2[h * 512 + j];
  }
  rpbt[h * 961 + m] = 16.f / (1.f + __expf(-acc));
}

__global__ __launch_bounds__(256) void xw_gather(const float* x, unsigned short* xw) {
  int idx = blockIdx.x * 256 + threadIdx.x;
  int m = idx >> 6, chunk = idx & 63;
  int win = m >> 8, tok = m & 255;
  int b = win >> 4, wh = (win >> 2) & 3, ww = win & 3;
  int tr = tok >> 4, tc = tok & 15;
  int sr = (wh * 16 + tr + 8) & 63, sc = (ww * 16 + tc + 8) & 63;
  const float* src = x + ((size_t)((b * 64 + sr) * 64 + sc)) * 512 + chunk * 8;
  float4 a = *(const float4*)src, bq = *(const float4*)(src + 4);
  ushort8 o;
  o[0] = f2bf(a.x); o[1] = f2bf(a.y); o[2] = f2bf(a.z); o[3] = f2bf(a.w);
  o[4] = f2bf(bq.x); o[5] = f2bf(bq.y); o[6] = f2bf(bq.z); o[7] = f2bf(bq.w);
  *(ushort8*)(xw + (size_t)m * 512 + chunk * 8) = o;
}

__global__ __launch_bounds__(256) void ln1_kernel(const unsigned short* pr, const float* x,
                                                  const float* gw, const float* bw,
                                                  unsigned short* x1b) {
  int w = threadIdx.x >> 6, lane = threadIdx.x & 63;
  size_t t = (size_t)blockIdx.x * 4 + w;
  int ti = (int)t;
  int b = ti >> 12, rc = ti & 4095, r = rc >> 6, c = rc & 63;
  int sr = (r + 56) & 63, sc = (c + 56) & 63;
  int win = b * 16 + (sr >> 4) * 4 + (sc >> 4);
  int tok = (sr & 15) * 16 + (sc & 15);
  int ch = lane * 8;
  ushort8 pv = *(const ushort8*)(pr + ((size_t)win * 256 + tok) * 512 + ch);
  float pf[8];
  float s = 0.f, s2 = 0.f;
#pragma unroll
  for (int j = 0; j < 8; j++) { pf[j] = bf2f(pv[j]); s += pf[j]; s2 += pf[j] * pf[j]; }
#pragma unroll
  for (int o = 1; o < 64; o <<= 1) { s += __shfl_xor(s, o, 64); s2 += __shfl_xor(s2, o, 64); }
  float mean = s * (1.f / 512.f);
  float rstd = rsqrtf(s2 * (1.f / 512.f) - mean * mean + 1e-5f);
  const float* xrow = x + t * 512 + ch;
  float4 xa = *(const float4*)xrow, xb = *(const float4*)(xrow + 4);
  float xs[8] = {xa.x, xa.y, xa.z, xa.w, xb.x, xb.y, xb.z, xb.w};
  ushort8 o8;
#pragma unroll
  for (int j = 0; j < 8; j++) {
    float y = (pf[j] - mean) * rstd * gw[ch + j] + bw[ch + j];
    o8[j] = f2bf(xs[j] + y);
  }
  *(ushort8*)(x1b + t * 512 + ch) = o8;
}

__global__ __launch_bounds__(256) void ln2_kernel(const unsigned short* mp,
                                                  const unsigned short* x1b, const float* gw,
                                                  const float* bw, float* out) {
  int w = threadIdx.x >> 6, lane = threadIdx.x & 63;
  size_t t = (size_t)blockIdx.x * 4 + w;
  int ch = lane * 8;
  ushort8 mv = *(const ushort8*)(mp + t * 512 + ch);
  float pf[8];
  float s = 0.f, s2 = 0.f;
#pragma unroll
  for (int j = 0; j < 8; j++) { pf[j] = bf2f(mv[j]); s += pf[j]; s2 += pf[j] * pf[j]; }
#pragma unroll
  for (int o = 1; o < 64; o <<= 1) { s += __shfl_xor(s, o, 64); s2 += __shfl_xor(s2, o, 64); }
  float mean = s * (1.f / 512.f);
  float rstd = rsqrtf(s2 * (1.f / 512.f) - mean * mean + 1e-5f);
  ushort8 xv = *(const ushort8*)(x1b + t * 512 + ch);
  float vals[8];
#pragma unroll
  for (int j = 0; j < 8; j++)
    vals[j] = bf2f(xv[j]) + (pf[j] - mean) * rstd * gw[ch + j] + bw[ch + j];
  *(float4*)(out + t * 512 + ch) = make_float4(vals[0], vals[1], vals[2], vals[3]);
  *(float4*)(out + t * 512 + ch + 4) = make_float4(vals[4], vals[5], vals[6], vals[7]);
}

// ------------------- launcher -------------------
extern "C" void kernel_launch(void* const* d_in, const int* in_sizes, int n_in, void* d_out,
                              int out_size, void* d_ws, size_t ws_size, hipStream_t stream) {
  (void)in_sizes; (void)n_in; (void)out_size; (void)ws_size;
  const float* x = (const float*)d_in[0];
  const float* qkv_w = (const float*)d_in[1];
  const float* q_bias = (const float*)d_in[2];
  const float* v_bias = (const float*)d_in[3];
  const float* logit_sc = (const float*)d_in[4];
  const float* cpb_w1 = (const float*)d_in[5];
  const float* cpb_b1 = (const float*)d_in[6];
  const float* cpb_w2 = (const float*)d_in[7];
  const float* proj_w = (const float*)d_in[8];
  const float* proj_b = (const float*)d_in[9];
  const float* n1g = (const float*)d_in[10];
  const float* n1b = (const float*)d_in[11];
  const float* n2g = (const float*)d_in[12];
  const float* n2b = (const float*)d_in[13];
  const float* fc1_w = (const float*)d_in[14];
  const float* fc1_b = (const float*)d_in[15];
  const float* fc2_w = (const float*)d_in[16];
  const float* fc2_b = (const float*)d_in[17];

  char* ws = (char*)d_ws;
  unsigned short* wq = (unsigned short*)(ws);                    // 1.5 MiB
  unsigned short* wp = (unsigned short*)(ws + (2ll << 20));      // 0.5 MiB
  unsigned short* w1 = (unsigned short*)(ws + (4ll << 20));      // 2 MiB
  unsigned short* w2 = (unsigned short*)(ws + (8ll << 20));      // 2 MiB
  float* rpbt = (float*)(ws + (12ll << 20));                     // 61.5 KB
  unsigned short* xw = (unsigned short*)(ws + (16ll << 20));     // 32 MiB (xw -> attn_out -> mlp_out)
  unsigned short* qbuf = (unsigned short*)(ws + (48ll << 20));   // 32 MiB
  unsigned short* kbuf = (unsigned short*)(ws + (80ll << 20));   // 32 MiB
  unsigned short* vbuf = (unsigned short*)(ws + (112ll << 20));  // 32 MiB
  unsigned short* projout = (unsigned short*)(ws + (144ll << 20));  // 32 MiB
  unsigned short* x1b = (unsigned short*)(ws + (176ll << 20));   // 32 MiB  (peak 208 MiB)
  unsigned short* hmid = (unsigned short*)(ws + (48ll << 20));   // 128 MiB, reuses qkv+projout
  unsigned short* mlpout = xw;                                   // reuses xw region
  float* out = (float*)d_out;

  cvt_bf16<<<dim3(384), dim3(256), 0, stream>>>(qkv_w, wq, 1536 * 512 / 8);
  cvt_bf16<<<dim3(128), dim3(256), 0, stream>>>(proj_w, wp, 512 * 512 / 8);
  cvt_bf16<<<dim3(512), dim3(256), 0, stream>>>(fc1_w, w1, 2048 * 512 / 8);
  cvt_bf16<<<dim3(512), dim3(256), 0, stream>>>(fc2_w, w2, 512 * 2048 / 8);
  cpb_kernel<<<dim3(61), dim3(256), 0, stream>>>(cpb_w1, cpb_b1, cpb_w2, rpbt);
  xw_gather<<<dim3(8192), dim3(256), 0, stream>>>(x, xw);

  // attention path (M=32768 rows of tokens)
  gemm_qkv<<<dim3(128, 6), dim3(512), 0, stream>>>(xw, wq, q_bias, v_bias, qbuf, kbuf, vbuf);
  attn_kernel<<<dim3(8192), dim3(256), 0, stream>>>(qbuf, kbuf, vbuf, rpbt, logit_sc, xw);
  gemm_epi<0><<<dim3(128, 2), dim3(512), 0, stream>>>(xw, wp, proj_b, projout, 512, 512);
  ln1_kernel<<<dim3(8192), dim3(256), 0, stream>>>(projout, x, n1g, n1b, x1b);

  // MLP path
  gemm_epi<1><<<dim3(128, 8), dim3(512), 0, stream>>>(x1b, w1, fc1_b, hmid, 2048, 512);
  gemm_epi<0><<<dim3(128, 2), dim3(512), 0, stream>>>(hmid, w2, fc2_b, mlpout, 512, 2048);
  ln2_kernel<<<dim3(8192), dim3(256), 0, stream>>>(mlpout, x1b, n2g, n2b, out);
}

// Round 10
// 467.046 us; speedup vs baseline: 1.0699x; 1.0699x over previous
//
#include <hip/hip_runtime.h>
#include <math.h>

// SwinV2 block, MI355X. All GEMMs in bf16 MFMA (16x16x32), fp32 accumulate.
// Round 10: GEMM mainloop reverted to R6 (best measured: quad-slot counted-vmcnt);
// q/k row-normalization folded into qkv GEMM epilogue (fp32, wave-shuffle reduce);
// attn: pre-normalized q/k + one-pass softmax (C = scale+16).
// Requires ws_size >= 208 MiB.

#define HEADS 16
#define HD 32
#define NTOK 256
#define DIMC 512
#define HIDDEN 2048

typedef __attribute__((ext_vector_type(8))) short bf16x8;
typedef __attribute__((ext_vector_type(4))) float f32x4;
typedef __attribute__((ext_vector_type(8))) unsigned short ushort8;

#define MFMA16(a, b, c) __builtin_amdgcn_mfma_f32_16x16x32_bf16((a), (b), (c), 0, 0, 0)
#define WAIT_VM(N) asm volatile("s_waitcnt vmcnt(" #N ")" ::: "memory")
#define WAIT_LGKM0 asm volatile("s_waitcnt lgkmcnt(0)" ::: "memory")

__device__ __forceinline__ unsigned short f2bf(float f) {
  union { float f; unsigned u; } v; v.f = f;
  unsigned r = v.u + 0x7FFFu + ((v.u >> 16) & 1u);
  return (unsigned short)(r >> 16);
}
__device__ __forceinline__ float bf2f(unsigned short h) {
  union { unsigned u; float f; } v; v.u = ((unsigned)h) << 16; return v.f;
}
__device__ __forceinline__ void gload16(const void* g, void* l) {
  __builtin_amdgcn_global_load_lds(
      (const __attribute__((address_space(1))) unsigned int*)g,
      (__attribute__((address_space(3))) unsigned int*)l, 16, 0, 0);
}
__device__ __forceinline__ bf16x8 ds_read128(const unsigned short* p) {
  unsigned off = (unsigned)(size_t)(const __attribute__((address_space(3))) unsigned short*)p;
  bf16x8 r;
  asm volatile("ds_read_b128 %0, %1" : "=v"(r) : "v"(off));
  return r;
}
__device__ __forceinline__ int band(int x) { return x < 48 ? 0 : (x < 56 ? 1 : 2); }

__device__ __forceinline__ float gelu_fast(float x) {
  float u2 = x * (1.5957691216f + 0.0713548163f * x * x);
  u2 = fminf(u2, 80.f);
  float e = __expf(u2);
  return x * (e / (e + 1.f));
}

// ------------------- 256x256 GEMM mainloop, 512 threads (8 waves, 2Mx4N) -------------------
// R6 structure (best measured): quad-slot ring, counted vmcnt, read-ahead fragments,
// one barrier per K-step.
__device__ __forceinline__ void gemm256_main(const unsigned short* Ab, const unsigned short* Bb,
                                             int K, unsigned short* aT, unsigned short* bT,
                                             f32x4 (&acc)[8][4]) {
  const int tid = threadIdx.x;
  const int w = tid >> 6, lane = tid & 63;
  const int cl = lane & 15, g = lane >> 4;
  const int wr = (w >> 2) * 128, wc = (w & 3) * 64;
  const int off0 = (2 * w) * 1024 + lane * 16;
  const int off1 = (2 * w + 1) * 1024 + lane * 16;
  const int r0 = off0 >> 6, c0 = ((off0 >> 4) & 3) ^ ((r0 >> 1) & 3);
  const int r1 = off1 >> 6, c1 = ((off1 >> 4) & 3) ^ ((r1 >> 1) & 3);
  const char* Ac = (const char*)Ab;
  const char* Bc = (const char*)Bb;
  const size_t sA0 = (size_t)r0 * (K * 2) + (size_t)c0 * 16;
  const size_t sA1 = (size_t)r1 * (K * 2) + (size_t)c1 * 16;
  const int T = K >> 5;
  int offB[4], offA0[4], offA1[4];
#pragma unroll
  for (int i = 0; i < 4; i++) {
    int rowb = wc + i * 16 + cl;
    offB[i] = rowb * 32 + ((g ^ ((rowb >> 1) & 3)) * 8);
    int rowa = wr + i * 16 + cl;
    offA0[i] = rowa * 32 + ((g ^ ((rowa >> 1) & 3)) * 8);
    int rowa1 = wr + 64 + i * 16 + cl;
    offA1[i] = rowa1 * 32 + ((g ^ ((rowa1 >> 1) & 3)) * 8);
  }
#pragma unroll
  for (int p = 0; p < 3; p++) {
    size_t kb = (size_t)p * 64;
    int bo = p * 16384;
    gload16(Ac + sA0 + kb, (char*)aT + bo + off0);
    gload16(Ac + sA1 + kb, (char*)aT + bo + off1);
    gload16(Bc + sA0 + kb, (char*)bT + bo + off0);
    gload16(Bc + sA1 + kb, (char*)bT + bo + off1);
  }
  WAIT_VM(8);
  __builtin_amdgcn_s_barrier();
  bf16x8 bfv[4], af[4];
#pragma unroll
  for (int ni = 0; ni < 4; ni++) bfv[ni] = ds_read128(bT + offB[ni]);
#pragma unroll
  for (int mi = 0; mi < 4; mi++) af[mi] = ds_read128(aT + offA0[mi]);

  for (int t = 0; t < T; t++) {
    const int cur = (t & 3) * 8192;
    if (t + 3 < T) {
      size_t kb = (size_t)(t + 3) * 64;
      int bo = ((t + 3) & 3) * 16384;
      gload16(Ac + sA0 + kb, (char*)aT + bo + off0);
      gload16(Ac + sA1 + kb, (char*)aT + bo + off1);
    }
    WAIT_LGKM0;
    __builtin_amdgcn_sched_barrier(0);
    __builtin_amdgcn_s_setprio(1);
#pragma unroll
    for (int mi = 0; mi < 4; mi++)
#pragma unroll
      for (int ni = 0; ni < 4; ni++) acc[mi][ni] = MFMA16(af[mi], bfv[ni], acc[mi][ni]);
    __builtin_amdgcn_s_setprio(0);
    bf16x8 af2[4];
#pragma unroll
    for (int mi = 0; mi < 4; mi++) af2[mi] = ds_read128(aT + cur + offA1[mi]);
    if (t + 3 < T) {
      size_t kb = (size_t)(t + 3) * 64;
      int bo = ((t + 3) & 3) * 16384;
      gload16(Bc + sA0 + kb, (char*)bT + bo + off0);
      gload16(Bc + sA1 + kb, (char*)bT + bo + off1);
    }
    WAIT_LGKM0;
    __builtin_amdgcn_sched_barrier(0);
    __builtin_amdgcn_s_setprio(1);
#pragma unroll
    for (int mi = 0; mi < 4; mi++)
#pragma unroll
      for (int ni = 0; ni < 4; ni++) acc[4 + mi][ni] = MFMA16(af2[mi], bfv[ni], acc[4 + mi][ni]);
    __builtin_amdgcn_s_setprio(0);
    if (t + 1 < T) {
      if (t + 3 < T) WAIT_VM(8);
      else if (t + 2 < T) WAIT_VM(4);
      else WAIT_VM(0);
      __builtin_amdgcn_s_barrier();
      const int nxt = ((t + 1) & 3) * 8192;
#pragma unroll
      for (int ni = 0; ni < 4; ni++) bfv[ni] = ds_read128(bT + nxt + offB[ni]);
#pragma unroll
      for (int mi = 0; mi < 4; mi++) af[mi] = ds_read128(aT + nxt + offA0[mi]);
    }
  }
}

__device__ __forceinline__ void xcd_swizzle(int& bm, int& bn) {
  int gy = gridDim.y;
  int nwg = gridDim.x * gy;
  int flat = blockIdx.y * gridDim.x + blockIdx.x;
  int cpx = nwg >> 3;
  int swz = (flat & 7) * cpx + (flat >> 3);
  bm = swz / gy;
  bn = swz % gy;
}

// ------------------- QKV GEMM: bias + q/k row-norm + scatter to q/k/v -------------------
// For q and k tiles, each (mi,reg) row-slice (one head = 32 cols) lives in one 16-lane
// cl-group x (ni pair) -> fp32 norm via 4x shfl_xor, then rsqrt, before the bf16 write.
__global__ __launch_bounds__(512, 2) void gemm_qkv(const unsigned short* A,
                                                   const unsigned short* Bw, const float* qbias,
                                                   const float* vbias, unsigned short* qo,
                                                   unsigned short* ko, unsigned short* vo) {
  __shared__ unsigned short aT[4 * 8192];
  __shared__ unsigned short bT[4 * 8192];
  int bm, bn;
  xcd_swizzle(bm, bn);
  f32x4 acc[8][4] = {};
  gemm256_main(A + (size_t)bm * 256 * DIMC, Bw + (size_t)bn * 256 * DIMC, DIMC, aT, bT, acc);
  int lane = threadIdx.x & 63, w = threadIdx.x >> 6;
  int wr = (w >> 2) * 128, wc = (w & 3) * 64, g = lane >> 4, cl = lane & 15;
  int which = bn >> 1;  // uniform per block: 0=q,1=k,2=v
  unsigned short* base = which == 0 ? qo : (which == 1 ? ko : vo);
  float bvv[4];
  int headv[4], hdv[4];
#pragma unroll
  for (int ni = 0; ni < 4; ni++) {
    int gn = bn * 256 + wc + ni * 16 + cl;
    int wn = gn & 511;
    headv[ni] = wn >> 5;
    hdv[ni] = wn & 31;
    bvv[ni] = (which == 0) ? qbias[wn] : (which == 2 ? vbias[wn] : 0.f);
  }
#pragma unroll
  for (int mi = 0; mi < 8; mi++) {
#pragma unroll
    for (int reg = 0; reg < 4; reg++) {
      int gm = bm * 256 + wr + mi * 16 + 4 * g + reg;
      int win = gm >> 8, tok = gm & 255;
      float v0 = acc[mi][0][reg] + bvv[0];
      float v1 = acc[mi][1][reg] + bvv[1];
      float v2 = acc[mi][2][reg] + bvv[2];
      float v3 = acc[mi][3][reg] + bvv[3];
      if (which <= 1) {  // normalize per head-row (uniform branch)
        float sA = v0 * v0 + v1 * v1;
        float sB = v2 * v2 + v3 * v3;
#pragma unroll
        for (int m = 1; m < 16; m <<= 1) {
          sA += __shfl_xor(sA, m, 64);
          sB += __shfl_xor(sB, m, 64);
        }
        float rA = rsqrtf(fmaxf(sA, 1e-24f));
        float rB = rsqrtf(fmaxf(sB, 1e-24f));
        v0 *= rA; v1 *= rA; v2 *= rB; v3 *= rB;
      }
      size_t rowb = ((size_t)(win * HEADS)) * NTOK * HD + (size_t)tok * HD;
      base[rowb + (size_t)headv[0] * NTOK * HD + hdv[0]] = f2bf(v0);
      base[rowb + (size_t)headv[1] * NTOK * HD + hdv[1]] = f2bf(v1);
      base[rowb + (size_t)headv[2] * NTOK * HD + hdv[2]] = f2bf(v2);
      base[rowb + (size_t)headv[3] * NTOK * HD + hdv[3]] = f2bf(v3);
    }
  }
}

// ------------------- generic GEMM: bias (+optional fast GELU) -> bf16 [M][N] -------------------
template <int GELU>
__global__ __launch_bounds__(512, 2) void gemm_epi(const unsigned short* A,
                                                   const unsigned short* Bw, const float* bias,
                                                   unsigned short* out, int N, int K) {
  __shared__ unsigned short aT[4 * 8192];
  __shared__ unsigned short bT[4 * 8192];
  int bm, bn;
  xcd_swizzle(bm, bn);
  f32x4 acc[8][4] = {};
  gemm256_main(A + (size_t)bm * 256 * K, Bw + (size_t)bn * 256 * K, K, aT, bT, acc);
  int lane = threadIdx.x & 63, w = threadIdx.x >> 6;
  int wr = (w >> 2) * 128, wc = (w & 3) * 64, g = lane >> 4, cl = lane & 15;
  float bv[4];
#pragma unroll
  for (int ni = 0; ni < 4; ni++) bv[ni] = bias[bn * 256 + wc + ni * 16 + cl];
#pragma unroll
  for (int mi = 0; mi < 8; mi++) {
#pragma unroll
    for (int reg = 0; reg < 4; reg++) {
      int gm = bm * 256 + wr + mi * 16 + 4 * g + reg;
      unsigned short* rowp = out + (size_t)gm * N + bn * 256 + wc + cl;
#pragma unroll
      for (int ni = 0; ni < 4; ni++) {
        float val = acc[mi][ni][reg] + bv[ni];
        if (GELU) val = gelu_fast(val);
        rowp[ni * 16] = f2bf(val);
      }
    }
  }
}

// ------------------- fused window attention -------------------
// block = (win, head, qb) ; q,k pre-normalized by gemm_qkv ; one-pass softmax
// (C = scale + 16 bounds S = scale*cos + rpb + mask).
__global__ __launch_bounds__(256) void attn_kernel(const unsigned short* qg,
                                                   const unsigned short* kg,
                                                   const unsigned short* vg, const float* rpbt,
                                                   const float* logit_scale,
                                                   unsigned short* attn_out) {
  __shared__ unsigned short kS[256 * 32];
  __shared__ unsigned short vT[32 * 256];
  __shared__ unsigned short pS[64 * 256];

  int bid = blockIdx.x;
  int qb = bid & 3, h = (bid >> 2) & 15, win = bid >> 6;
  int tid = threadIdx.x, lane = tid & 63, w = tid >> 6;
  int g = lane >> 4, cl = lane & 15;
  const size_t whbase = ((size_t)(win * HEADS + h)) * NTOK * HD;
  const unsigned short* qwin = qg + whbase + (size_t)qb * 64 * HD;
  const unsigned short* kwin = kg + whbase;
  const unsigned short* vwin = vg + whbase;

#pragma unroll
  for (int i = 0; i < 4; i++) {
    int ci = i * 256 + tid, row = ci >> 2, gc = ci & 3;
    uint4 d = *(const uint4*)(kwin + row * 32 + gc * 8);
    *(uint4*)(kS + row * 32 + ((gc ^ ((row >> 1) & 3)) * 8)) = d;
  }
  {
    int tok = tid;
    ushort8 t0 = *(const ushort8*)(vwin + tok * 32);
    ushort8 t1 = *(const ushort8*)(vwin + tok * 32 + 8);
    ushort8 t2 = *(const ushort8*)(vwin + tok * 32 + 16);
    ushort8 t3 = *(const ushort8*)(vwin + tok * 32 + 24);
    int kc = tok >> 3, ki = tok & 7;
#pragma unroll
    for (int j = 0; j < 8; j++) {
      vT[(j)*256 + ((kc ^ (j & 7)) << 3) + ki] = t0[j];
      vT[(8 + j) * 256 + ((kc ^ ((8 + j) & 7)) << 3) + ki] = t1[j];
      vT[(16 + j) * 256 + ((kc ^ ((16 + j) & 7)) << 3) + ki] = t2[j];
      vT[(24 + j) * 256 + ((kc ^ ((24 + j) & 7)) << 3) + ki] = t3[j];
    }
  }

  float scale = __expf(fminf(logit_scale[h], 4.6051702f));

  // q fragment: pre-normalized, just apply scale
  bf16x8 qf;
  {
    int qrow = 16 * w + cl;
    ushort8 qraw = *(const ushort8*)(qwin + qrow * 32 + 8 * g);
#pragma unroll
    for (int j = 0; j < 8; j++) qf[j] = (short)f2bf(bf2f(qraw[j]) * scale);
  }
  __syncthreads();

  // S = q @ K^T : 16 tiles of 16x16
  f32x4 acc[16];
#pragma unroll
  for (int ct = 0; ct < 16; ct++) {
    int kr = ct * 16 + cl;
    bf16x8 kf = *(const bf16x8*)(kS + kr * 32 + ((g ^ ((kr >> 1) & 3)) * 8));
    f32x4 z = {0.f, 0.f, 0.f, 0.f};
    acc[ct] = MFMA16(qf, kf, z);
  }

  // one-pass: + rpb + mask -> p = exp(S - C) -> LDS ; row sums
  int wh = (win >> 2) & 3, ww = win & 3;
  int bandcc = band(ww * 16 + cl);
  const float* rpbh = rpbt + h * 961;
  const float C = scale + 16.f;
  int baseidx[4], ridq[4];
#pragma unroll
  for (int reg = 0; reg < 4; reg++) {
    int qrow = qb * 64 + 16 * w + 4 * g + reg;
    int ri = qrow >> 4, ci = qrow & 15;
    ridq[reg] = 3 * band(wh * 16 + ri) + band(ww * 16 + ci);
    baseidx[reg] = (ri + 15) * 31 + (ci + 15 - cl);
  }
  float s4[4] = {0.f, 0.f, 0.f, 0.f};
#pragma unroll
  for (int ct = 0; ct < 16; ct++) {
    int brc = 3 * band(wh * 16 + ct);
#pragma unroll
    for (int reg = 0; reg < 4; reg++) {
      float v = acc[ct][reg] + rpbh[baseidx[reg] - ct * 31] +
                ((ridq[reg] != (brc + bandcc)) ? -100.f : 0.f);
      float p = __expf(v - C);
      s4[reg] += p;
      int row = 16 * w + 4 * g + reg;
      int c = ct * 16 + cl;
      pS[row * 256 + (((c >> 3) ^ (row & 7)) << 3) + (c & 7)] = f2bf(p);
    }
  }
#pragma unroll
  for (int reg = 0; reg < 4; reg++) {
#pragma unroll
    for (int o = 1; o < 16; o <<= 1) s4[reg] += __shfl_xor(s4[reg], o, 64);
  }

  // O = P @ V  (wave reads only its own P rows -> no barrier needed)
  f32x4 o0 = {0.f, 0.f, 0.f, 0.f}, o1 = {0.f, 0.f, 0.f, 0.f};
  int prow = 16 * w + cl;
#pragma unroll
  for (int ks = 0; ks < 8; ks++) {
    bf16x8 pf = *(const bf16x8*)(pS + prow * 256 + ((((ks * 4 + g)) ^ (prow & 7)) << 3));
    int kc = ks * 4 + g;
    bf16x8 vf0 = *(const bf16x8*)(vT + cl * 256 + ((kc ^ (cl & 7)) << 3));
    bf16x8 vf1 = *(const bf16x8*)(vT + (16 + cl) * 256 + ((kc ^ ((16 + cl) & 7)) << 3));
    o0 = MFMA16(pf, vf0, o0);
    o1 = MFMA16(pf, vf1, o1);
  }

#pragma unroll
  for (int reg = 0; reg < 4; reg++) {
    int row = 16 * w + 4 * g + reg;
    float linv = 1.f / s4[reg];
    size_t tokg = (size_t)win * NTOK + qb * 64 + row;
    attn_out[tokg * DIMC + h * 32 + cl] = f2bf(o0[reg] * linv);
    attn_out[tokg * DIMC + h * 32 + 16 + cl] = f2bf(o1[reg] * linv);
  }
}

// ------------------- prep kernels -------------------
__global__ __launch_bounds__(256) void cvt_bf16(const float* src, unsigned short* dst, int n8) {
  int i = blockIdx.x * 256 + threadIdx.x;
  if (i >= n8) return;
  const float* s = src + (size_t)i * 8;
  float4 a = *(const float4*)s, b = *(const float4*)(s + 4);
  ushort8 o;
  o[0] = f2bf(a.x); o[1] = f2bf(a.y); o[2] = f2bf(a.z); o[3] = f2bf(a.w);
  o[4] = f2bf(b.x); o[5] = f2bf(b.y); o[6] = f2bf(b.z); o[7] = f2bf(b.w);
  *(ushort8*)(dst + (size_t)i * 8) = o;
}

__device__ __forceinline__ float cpb_coord(int i) {
  float t = (float)(i - 15) * (8.f / 15.f);
  float s = (t > 0.f) ? 1.f : ((t < 0.f) ? -1.f : 0.f);
  return s * log2f(fabsf(t) + 1.f) * (1.f / 3.f);
}

__global__ __launch_bounds__(256) void cpb_kernel(const float* w1, const float* b1, const float* w2,
                                                  float* rpbt) {
  int i = blockIdx.x * 256 + threadIdx.x;
  if (i >= 961 * 16) return;
  int m = i >> 4, h = i & 15;
  int mi = m / 31, mj = m % 31;
  float c0 = cpb_coord(mi), c1 = cpb_coord(mj);
  float acc = 0.f;
  for (int j = 0; j < 512; j++) {
    float hv = fmaxf(w1[2 * j] * c0 + w1[2 * j + 1] * c1 + b1[j], 0.f);
    acc += hv * w2[h * 512 + j];
  }
  rpbt[h * 961 + m] = 16.f / (1.f + __expf(-acc));
}

__global__ __launch_bounds__(256) void xw_gather(const float* x, unsigned short* xw) {
  int idx = blockIdx.x * 256 + threadIdx.x;
  int m = idx >> 6, chunk = idx & 63;
  int win = m >> 8, tok = m & 255;
  int b = win >> 4, wh = (win >> 2) & 3, ww = win & 3;
  int tr = tok >> 4, tc = tok & 15;
  int sr = (wh * 16 + tr + 8) & 63, sc = (ww * 16 + tc + 8) & 63;
  const float* src = x + ((size_t)((b * 64 + sr) * 64 + sc)) * 512 + chunk * 8;
  float4 a = *(const float4*)src, bq = *(const float4*)(src + 4);
  ushort8 o;
  o[0] = f2bf(a.x); o[1] = f2bf(a.y); o[2] = f2bf(a.z); o[3] = f2bf(a.w);
  o[4] = f2bf(bq.x); o[5] = f2bf(bq.y); o[6] = f2bf(bq.z); o[7] = f2bf(bq.w);
  *(ushort8*)(xw + (size_t)m * 512 + chunk * 8) = o;
}

__global__ __launch_bounds__(256) void ln1_kernel(const unsigned short* pr, const float* x,
                                                  const float* gw, const float* bw,
                                                  unsigned short* x1b) {
  int w = threadIdx.x >> 6, lane = threadIdx.x & 63;
  size_t t = (size_t)blockIdx.x * 4 + w;
  int ti = (int)t;
  int b = ti >> 12, rc = ti & 4095, r = rc >> 6, c = rc & 63;
  int sr = (r + 56) & 63, sc = (c + 56) & 63;
  int win = b * 16 + (sr >> 4) * 4 + (sc >> 4);
  int tok = (sr & 15) * 16 + (sc & 15);
  int ch = lane * 8;
  ushort8 pv = *(const ushort8*)(pr + ((size_t)win * 256 + tok) * 512 + ch);
  float pf[8];
  float s = 0.f, s2 = 0.f;
#pragma unroll
  for (int j = 0; j < 8; j++) { pf[j] = bf2f(pv[j]); s += pf[j]; s2 += pf[j] * pf[j]; }
#pragma unroll
  for (int o = 1; o < 64; o <<= 1) { s += __shfl_xor(s, o, 64); s2 += __shfl_xor(s2, o, 64); }
  float mean = s * (1.f / 512.f);
  float rstd = rsqrtf(s2 * (1.f / 512.f) - mean * mean + 1e-5f);
  const float* xrow = x + t * 512 + ch;
  float4 xa = *(const float4*)xrow, xb = *(const float4*)(xrow + 4);
  float xs[8] = {xa.x, xa.y, xa.z, xa.w, xb.x, xb.y, xb.z, xb.w};
  ushort8 o8;
#pragma unroll
  for (int j = 0; j < 8; j++) {
    float y = (pf[j] - mean) * rstd * gw[ch + j] + bw[ch + j];
    o8[j] = f2bf(xs[j] + y);
  }
  *(ushort8*)(x1b + t * 512 + ch) = o8;
}

__global__ __launch_bounds__(256) void ln2_kernel(const unsigned short* mp,
                                                  const unsigned short* x1b, const float* gw,
                                                  const float* bw, float* out) {
  int w = threadIdx.x >> 6, lane = threadIdx.x & 63;
  size_t t = (size_t)blockIdx.x * 4 + w;
  int ch = lane * 8;
  ushort8 mv = *(const ushort8*)(mp + t * 512 + ch);
  float pf[8];
  float s = 0.f, s2 = 0.f;
#pragma unroll
  for (int j = 0; j < 8; j++) { pf[j] = bf2f(mv[j]); s += pf[j]; s2 += pf[j] * pf[j]; }
#pragma unroll
  for (int o = 1; o < 64; o <<= 1) { s += __shfl_xor(s, o, 64); s2 += __shfl_xor(s2, o, 64); }
  float mean = s * (1.f / 512.f);
  float rstd = rsqrtf(s2 * (1.f / 512.f) - mean * mean + 1e-5f);
  ushort8 xv = *(const ushort8*)(x1b + t * 512 + ch);
  float vals[8];
#pragma unroll
  for (int j = 0; j < 8; j++)
    vals[j] = bf2f(xv[j]) + (pf[j] - mean) * rstd * gw[ch + j] + bw[ch + j];
  *(float4*)(out + t * 512 + ch) = make_float4(vals[0], vals[1], vals[2], vals[3]);
  *(float4*)(out + t * 512 + ch + 4) = make_float4(vals[4], vals[5], vals[6], vals[7]);
}

// ------------------- launcher -------------------
extern "C" void kernel_launch(void* const* d_in, const int* in_sizes, int n_in, void* d_out,
                              int out_size, void* d_ws, size_t ws_size, hipStream_t stream) {
  (void)in_sizes; (void)n_in; (void)out_size; (void)ws_size;
  const float* x = (const float*)d_in[0];
  const float* qkv_w = (const float*)d_in[1];
  const float* q_bias = (const float*)d_in[2];
  const float* v_bias = (const float*)d_in[3];
  const float* logit_sc = (const float*)d_in[4];
  const float* cpb_w1 = (const float*)d_in[5];
  const float* cpb_b1 = (const float*)d_in[6];
  const float* cpb_w2 = (const float*)d_in[7];
  const float* proj_w = (const float*)d_in[8];
  const float* proj_b = (const float*)d_in[9];
  const float* n1g = (const float*)d_in[10];
  const float* n1b = (const float*)d_in[11];
  const float* n2g = (const float*)d_in[12];
  const float* n2b = (const float*)d_in[13];
  const float* fc1_w = (const float*)d_in[14];
  const float* fc1_b = (const float*)d_in[15];
  const float* fc2_w = (const float*)d_in[16];
  const float* fc2_b = (const float*)d_in[17];

  char* ws = (char*)d_ws;
  unsigned short* wq = (unsigned short*)(ws);                    // 1.5 MiB
  unsigned short* wp = (unsigned short*)(ws + (2ll << 20));      // 0.5 MiB
  unsigned short* w1 = (unsigned short*)(ws + (4ll << 20));      // 2 MiB
  unsigned short* w2 = (unsigned short*)(ws + (8ll << 20));      // 2 MiB
  float* rpbt = (float*)(ws + (12ll << 20));                     // 61.5 KB
  unsigned short* xw = (unsigned short*)(ws + (16ll << 20));     // 32 MiB (xw -> attn_out -> mlp_out)
  unsigned short* qbuf = (unsigned short*)(ws + (48ll << 20));   // 32 MiB
  unsigned short* kbuf = (unsigned short*)(ws + (80ll << 20));   // 32 MiB
  unsigned short* vbuf = (unsigned short*)(ws + (112ll << 20));  // 32 MiB
  unsigned short* projout = (unsigned short*)(ws + (144ll << 20));  // 32 MiB
  unsigned short* x1b = (unsigned short*)(ws + (176ll << 20));   // 32 MiB  (peak 208 MiB)
  unsigned short* hmid = (unsigned short*)(ws + (48ll << 20));   // 128 MiB, reuses qkv+projout
  unsigned short* mlpout = xw;                                   // reuses xw region
  float* out = (float*)d_out;

  cvt_bf16<<<dim3(384), dim3(256), 0, stream>>>(qkv_w, wq, 1536 * 512 / 8);
  cvt_bf16<<<dim3(128), dim3(256), 0, stream>>>(proj_w, wp, 512 * 512 / 8);
  cvt_bf16<<<dim3(512), dim3(256), 0, stream>>>(fc1_w, w1, 2048 * 512 / 8);
  cvt_bf16<<<dim3(512), dim3(256), 0, stream>>>(fc2_w, w2, 512 * 2048 / 8);
  cpb_kernel<<<dim3(61), dim3(256), 0, stream>>>(cpb_w1, cpb_b1, cpb_w2, rpbt);
  xw_gather<<<dim3(8192), dim3(256), 0, stream>>>(x, xw);

  // attention path (M=32768 rows of tokens)
  gemm_qkv<<<dim3(128, 6), dim3(512), 0, stream>>>(xw, wq, q_bias, v_bias, qbuf, kbuf, vbuf);
  attn_kernel<<<dim3(8192), dim3(256), 0, stream>>>(qbuf, kbuf, vbuf, rpbt, logit_sc, xw);
  gemm_epi<0><<<dim3(128, 2), dim3(512), 0, stream>>>(xw, wp, proj_b, projout, 512, 512);
  ln1_kernel<<<dim3(8192), dim3(256), 0, stream>>>(projout, x, n1g, n1b, x1b);

  // MLP path
  gemm_epi<1><<<dim3(128, 8), dim3(512), 0, stream>>>(x1b, w1, fc1_b, hmid, 2048, 512);
  gemm_epi<0><<<dim3(128, 2), dim3(512), 0, stream>>>(hmid, w2, fc2_b, mlpout, 512, 2048);
  ln2_kernel<<<dim3(8192), dim3(256), 0, stream>>>(mlpout, x1b, n2g, n2b, out);
}